// Round 1
// baseline (582.918 us; speedup 1.0000x reference)
//
#include <hip/hip_runtime.h>

// Fused transformer block: B=2048, T=128, DM=32, H=2, DK=16, fp32.
// One workgroup per batch element; whole (T x DM) tile staged in LDS.
// LDS budget: xbuf 128*33*4 = 16896 B, region 8320*4 = 33280 B -> 50176 B total
// => 3 workgroups/CU (150.5 KB of 160 KB), 12 waves/CU.

constexpr int T  = 128;
constexpr int DM = 32;
constexpr int DK = 16;
constexpr int XS = DM + 1;   // padded x-tile row stride (bank-conflict-free column walks)
constexpr int HS = 65;       // padded FFN h-chunk row stride
constexpr int REGION = 8320; // kb(4096)+vb(4096); attnT(4096) aliases kb; hch(8320) aliases all

__global__ __launch_bounds__(256, 3) void fused_transformer_block(
    const float* __restrict__ x,
    const float* __restrict__ Wq,
    const float* __restrict__ Wk,
    const float* __restrict__ Wv,
    const float* __restrict__ Wo,
    const float* __restrict__ bo,
    const float* __restrict__ W1,
    const float* __restrict__ b1,
    const float* __restrict__ W2,
    const float* __restrict__ b2,
    const float* __restrict__ g1,
    const float* __restrict__ beta1,
    const float* __restrict__ g2,
    const float* __restrict__ beta2,
    float* __restrict__ out)
{
    __shared__ float xbuf[T * XS];
    __shared__ float region[REGION];

    float* kb    = region;              // [H][T][DK]
    float* vb    = region + 2 * T * DK; // offset 4096
    float* attnT = region;              // [H*DK][T], aliases kb (valid after barrier)
    float* hch   = region;              // [T][HS], aliases everything (valid after Wo)

    const int tid = threadIdx.x;
    const int b   = blockIdx.x;
    const float* __restrict__ xg = x + (size_t)b * (T * DM);

    // ---------- phase 0: load x tile (coalesced float4 global, scalar LDS stores due to pad) ----------
    for (int o4 = tid; o4 < T * DM / 4; o4 += 256) {
        const float4 v = reinterpret_cast<const float4*>(xg)[o4];
        const int t = o4 >> 3;
        const int d = (o4 & 7) * 4;
        float* p = xbuf + t * XS + d;
        p[0] = v.x; p[1] = v.y; p[2] = v.z; p[3] = v.w;
    }
    __syncthreads();

    // ---------- phase 1: LayerNorm 1 (one row per thread; stride-33 rows -> 2-way bank = free) ----------
    if (tid < T) {
        float* row = xbuf + tid * XS;
        float s = 0.f, s2 = 0.f;
        #pragma unroll
        for (int m = 0; m < DM; ++m) { const float v = row[m]; s += v; s2 = fmaf(v, v, s2); }
        const float mu  = s * (1.f / DM);
        const float var = s2 * (1.f / DM) - mu * mu;
        const float inv = rsqrtf(var + 1e-5f);
        #pragma unroll
        for (int m = 0; m < DM; ++m)
            row[m] = (row[m] - mu) * inv * g1[m] + beta1[m];
    }
    __syncthreads();

    // ---------- phase 2: Q in registers, K/V -> LDS. thread = (head h, row tq) ----------
    const int h  = tid >> 7;
    const int tq = tid & 127;
    float qv[DK], kr[DK], vr[DK];
    #pragma unroll
    for (int d = 0; d < DK; ++d) { qv[d] = 0.f; kr[d] = 0.f; vr[d] = 0.f; }
    {
        const float* __restrict__ wq = Wq + h * DM * DK;
        const float* __restrict__ wk = Wk + h * DM * DK;
        const float* __restrict__ wv = Wv + h * DM * DK;
        const float* __restrict__ xrow = xbuf + tq * XS;
        for (int m = 0; m < DM; ++m) {
            const float xv = xrow[m];
            const float4* wq4 = reinterpret_cast<const float4*>(wq + m * DK);
            const float4* wk4 = reinterpret_cast<const float4*>(wk + m * DK);
            const float4* wv4 = reinterpret_cast<const float4*>(wv + m * DK);
            #pragma unroll
            for (int g = 0; g < 4; ++g) {
                const float4 a = wq4[g], c = wk4[g], e = wv4[g];
                qv[g*4+0] = fmaf(xv, a.x, qv[g*4+0]);
                qv[g*4+1] = fmaf(xv, a.y, qv[g*4+1]);
                qv[g*4+2] = fmaf(xv, a.z, qv[g*4+2]);
                qv[g*4+3] = fmaf(xv, a.w, qv[g*4+3]);
                kr[g*4+0] = fmaf(xv, c.x, kr[g*4+0]);
                kr[g*4+1] = fmaf(xv, c.y, kr[g*4+1]);
                kr[g*4+2] = fmaf(xv, c.z, kr[g*4+2]);
                kr[g*4+3] = fmaf(xv, c.w, kr[g*4+3]);
                vr[g*4+0] = fmaf(xv, e.x, vr[g*4+0]);
                vr[g*4+1] = fmaf(xv, e.y, vr[g*4+1]);
                vr[g*4+2] = fmaf(xv, e.z, vr[g*4+2]);
                vr[g*4+3] = fmaf(xv, e.w, vr[g*4+3]);
            }
        }
        float* kdst = kb + (h * T + tq) * DK;
        float* vdst = vb + (h * T + tq) * DK;
        #pragma unroll
        for (int g = 0; g < 4; ++g) {
            reinterpret_cast<float4*>(kdst)[g] = make_float4(kr[g*4+0], kr[g*4+1], kr[g*4+2], kr[g*4+3]);
            reinterpret_cast<float4*>(vdst)[g] = make_float4(vr[g*4+0], vr[g*4+1], vr[g*4+2], vr[g*4+3]);
        }
    }
    __syncthreads();

    // ---------- phase 3: causal attention, online softmax (no score scaling per reference) ----------
    // scores are O(1) (var ~1.8); max over all samples ~10 => raw expf is safe in fp32.
    float acc[DK];
    #pragma unroll
    for (int d = 0; d < DK; ++d) acc[d] = 0.f;
    float lsum = 0.f;
    {
        const float4* k4 = reinterpret_cast<const float4*>(kb + h * T * DK);
        const float4* v4 = reinterpret_cast<const float4*>(vb + h * T * DK);
        for (int s = 0; s <= tq; ++s) {
            const float4 k0 = k4[s*4+0], k1 = k4[s*4+1], k2 = k4[s*4+2], k3 = k4[s*4+3];
            float p0 = fmaf(qv[0],  k0.x, fmaf(qv[1],  k0.y, fmaf(qv[2],  k0.z, qv[3]  * k0.w)));
            float p1 = fmaf(qv[4],  k1.x, fmaf(qv[5],  k1.y, fmaf(qv[6],  k1.z, qv[7]  * k1.w)));
            float p2 = fmaf(qv[8],  k2.x, fmaf(qv[9],  k2.y, fmaf(qv[10], k2.z, qv[11] * k2.w)));
            float p3 = fmaf(qv[12], k3.x, fmaf(qv[13], k3.y, fmaf(qv[14], k3.z, qv[15] * k3.w)));
            const float sc = (p0 + p1) + (p2 + p3);
            const float p = __expf(sc);
            lsum += p;
            const float4 v0 = v4[s*4+0], v1 = v4[s*4+1], v2 = v4[s*4+2], v3 = v4[s*4+3];
            acc[0]  = fmaf(p, v0.x, acc[0]);
            acc[1]  = fmaf(p, v0.y, acc[1]);
            acc[2]  = fmaf(p, v0.z, acc[2]);
            acc[3]  = fmaf(p, v0.w, acc[3]);
            acc[4]  = fmaf(p, v1.x, acc[4]);
            acc[5]  = fmaf(p, v1.y, acc[5]);
            acc[6]  = fmaf(p, v1.z, acc[6]);
            acc[7]  = fmaf(p, v1.w, acc[7]);
            acc[8]  = fmaf(p, v2.x, acc[8]);
            acc[9]  = fmaf(p, v2.y, acc[9]);
            acc[10] = fmaf(p, v2.z, acc[10]);
            acc[11] = fmaf(p, v2.w, acc[11]);
            acc[12] = fmaf(p, v3.x, acc[12]);
            acc[13] = fmaf(p, v3.y, acc[13]);
            acc[14] = fmaf(p, v3.z, acc[14]);
            acc[15] = fmaf(p, v3.w, acc[15]);
        }
    }
    const float linv = 1.f / lsum;
    #pragma unroll
    for (int d = 0; d < DK; ++d) acc[d] *= linv;
    __syncthreads();   // all kb/vb reads done before attnT (aliases kb) is written
    #pragma unroll
    for (int d = 0; d < DK; ++d)
        attnT[(h * DK + d) * T + tq] = acc[d];   // coalesced LDS stores (consecutive tq per lane)
    __syncthreads();

    // ---------- phase 4: x2 = x1 + attn @ Wo + bo (in-place in xbuf; each element single-owner) ----------
    const int tr = tid >> 1;
    const int d0 = (tid & 1) * 16;
    {
        float a2[16];
        #pragma unroll
        for (int i = 0; i < 16; ++i) a2[i] = xbuf[tr * XS + d0 + i] + bo[d0 + i];
        for (int m = 0; m < DM; ++m) {
            const float av = attnT[m * T + tr];
            const float4* w4 = reinterpret_cast<const float4*>(Wo + m * DM + d0);
            #pragma unroll
            for (int g = 0; g < 4; ++g) {
                const float4 w = w4[g];
                a2[g*4+0] = fmaf(av, w.x, a2[g*4+0]);
                a2[g*4+1] = fmaf(av, w.y, a2[g*4+1]);
                a2[g*4+2] = fmaf(av, w.z, a2[g*4+2]);
                a2[g*4+3] = fmaf(av, w.w, a2[g*4+3]);
            }
        }
        #pragma unroll
        for (int i = 0; i < 16; ++i) xbuf[tr * XS + d0 + i] = a2[i];
    }
    __syncthreads();

    // ---------- phase 5: LayerNorm 2 (in-place; FFN residual comes from LN2 output, per reference) ----------
    if (tid < T) {
        float* row = xbuf + tid * XS;
        float s = 0.f, s2 = 0.f;
        #pragma unroll
        for (int m = 0; m < DM; ++m) { const float v = row[m]; s += v; s2 = fmaf(v, v, s2); }
        const float mu  = s * (1.f / DM);
        const float var = s2 * (1.f / DM) - mu * mu;
        const float inv = rsqrtf(var + 1e-5f);
        #pragma unroll
        for (int m = 0; m < DM; ++m)
            row[m] = (row[m] - mu) * inv * g2[m] + beta2[m];
    }
    __syncthreads();

    // ---------- phase 6: FFN, two 64-column passes. out = x3 + relu(x3@W1 + b1)@W2 + b2 ----------
    float oacc[16];
    #pragma unroll
    for (int i = 0; i < 16; ++i) oacc[i] = xbuf[tr * XS + d0 + i] + b2[d0 + i];

    for (int p = 0; p < 2; ++p) {
        __syncthreads();   // protect hch overwrite (aliases kb/vb/attnT; prev consumption done)
        {
            const int jj0 = (tid & 1) * 32;
            float hacc[32];
            const float* b1p = b1 + p * 64 + jj0;
            #pragma unroll
            for (int i = 0; i < 32; ++i) hacc[i] = b1p[i];
            for (int m = 0; m < DM; ++m) {
                const float xv = xbuf[tr * XS + m];
                const float4* w4 = reinterpret_cast<const float4*>(W1 + m * 128 + p * 64 + jj0);
                #pragma unroll
                for (int g = 0; g < 8; ++g) {
                    const float4 w = w4[g];
                    hacc[g*4+0] = fmaf(xv, w.x, hacc[g*4+0]);
                    hacc[g*4+1] = fmaf(xv, w.y, hacc[g*4+1]);
                    hacc[g*4+2] = fmaf(xv, w.z, hacc[g*4+2]);
                    hacc[g*4+3] = fmaf(xv, w.w, hacc[g*4+3]);
                }
            }
            float* hdst = hch + tr * HS + jj0;
            #pragma unroll
            for (int i = 0; i < 32; ++i) hdst[i] = fmaxf(hacc[i], 0.f);
        }
        __syncthreads();
        for (int jj = 0; jj < 64; ++jj) {
            const float hv = hch[tr * HS + jj];   // broadcast within lane-pairs, stride-65 rows -> conflict-free
            const float4* w4 = reinterpret_cast<const float4*>(W2 + (p * 64 + jj) * DM + d0);
            #pragma unroll
            for (int g = 0; g < 4; ++g) {
                const float4 w = w4[g];
                oacc[g*4+0] = fmaf(hv, w.x, oacc[g*4+0]);
                oacc[g*4+1] = fmaf(hv, w.y, oacc[g*4+1]);
                oacc[g*4+2] = fmaf(hv, w.z, oacc[g*4+2]);
                oacc[g*4+3] = fmaf(hv, w.w, oacc[g*4+3]);
            }
        }
    }

    // ---------- phase 7: write out (coalesced float4) ----------
    float* og = out + (size_t)b * (T * DM) + tr * DM + d0;
    #pragma unroll
    for (int g = 0; g < 4; ++g)
        reinterpret_cast<float4*>(og)[g] = make_float4(oacc[g*4+0], oacc[g*4+1], oacc[g*4+2], oacc[g*4+3]);
}

extern "C" void kernel_launch(void* const* d_in, const int* in_sizes, int n_in,
                              void* d_out, int out_size, void* d_ws, size_t ws_size,
                              hipStream_t stream) {
    const float* x   = (const float*)d_in[0];
    const float* Wq  = (const float*)d_in[1];
    const float* Wk  = (const float*)d_in[2];
    const float* Wv  = (const float*)d_in[3];
    const float* Wo  = (const float*)d_in[4];
    const float* bo  = (const float*)d_in[5];
    const float* W1  = (const float*)d_in[6];
    const float* b1  = (const float*)d_in[7];
    const float* W2  = (const float*)d_in[8];
    const float* b2  = (const float*)d_in[9];
    const float* g1  = (const float*)d_in[10];
    const float* be1 = (const float*)d_in[11];
    const float* g2  = (const float*)d_in[12];
    const float* be2 = (const float*)d_in[13];
    float* outp = (float*)d_out;

    hipLaunchKernelGGL(fused_transformer_block, dim3(2048), dim3(256), 0, stream,
                       x, Wq, Wk, Wv, Wo, bo, W1, b1, W2, b2, g1, be1, g2, be2, outp);
}

// Round 2
// 257.689 us; speedup vs baseline: 2.2621x; 2.2621x over previous
//
#include <hip/hip_runtime.h>

// Fused transformer block, split into 3 stream-ordered kernels.
// B=2048, T=128, DM=32, H=2, DK=16.  Intermediates bf16 in d_ws (83.9 MB):
//   xln [B*T][32], q/k/v [B][H][T][DK], x3 [B*T][32]
// kA: LN1 + QKV projection (VALU, weights in LDS, coalesced bf16 stores)
// kB: causal attention + Wo + residual + LN2 (per-row fp32, K/V in LDS)
// kC: FFN via MFMA 16x16x32 bf16 (K=32 == DM; W frags in registers)

typedef __attribute__((ext_vector_type(8))) short short8x;
typedef __attribute__((ext_vector_type(4))) float f32x4;

__device__ __forceinline__ unsigned short f2bf(float f) {
    union { float f; unsigned u; } c; c.f = f;
    return (unsigned short)((c.u + 0x7FFFu + ((c.u >> 16) & 1u)) >> 16);
}
__device__ __forceinline__ float bf2f(unsigned short s) {
    union { unsigned u; float f; } c; c.u = ((unsigned)s) << 16;
    return c.f;
}
__device__ __forceinline__ float bflo(unsigned u) { union { unsigned x; float f; } c; c.x = u << 16; return c.f; }
__device__ __forceinline__ float bfhi(unsigned u) { union { unsigned x; float f; } c; c.x = u & 0xFFFF0000u; return c.f; }

// ---------------------------------------------------------------- kernel A
// grid 512, block 256. Each block: 512 rows (4 batch elems). 2 rows/thread.
__global__ __launch_bounds__(256, 2) void kA(
    const float* __restrict__ x, const float* __restrict__ Wq,
    const float* __restrict__ Wk, const float* __restrict__ Wv,
    const float* __restrict__ g1, const float* __restrict__ beta1,
    unsigned short* __restrict__ xln, unsigned short* __restrict__ qw,
    unsigned short* __restrict__ kw, unsigned short* __restrict__ vw)
{
    __shared__ float Wsh[3072];              // [mat][h][m][dk] f32, 12.3 KB
    __shared__ unsigned short st[512 * 36];  // bf16 staging, rows padded to 36 (72 B)
    const int tid = threadIdx.x;
    const size_t blk = blockIdx.x;

    for (int i = tid; i < 3072; i += 256) {
        const float* src = (i < 1024) ? Wq : (i < 2048 ? Wk : Wv);
        Wsh[i] = src[i & 1023];
    }

    // load 2 rows direct (8 float4 per row hit one 128B line), LN1 in regs
    float xr[2][32];
    #pragma unroll
    for (int rr = 0; rr < 2; ++rr) {
        const int r = tid + rr * 256;
        const float4* xp = reinterpret_cast<const float4*>(x + (blk * 512 + r) * 32);
        float s = 0.f, s2 = 0.f;
        #pragma unroll
        for (int i = 0; i < 8; ++i) {
            float4 v = xp[i];
            xr[rr][i*4+0] = v.x; xr[rr][i*4+1] = v.y; xr[rr][i*4+2] = v.z; xr[rr][i*4+3] = v.w;
        }
        #pragma unroll
        for (int m = 0; m < 32; ++m) { const float v = xr[rr][m]; s += v; s2 = fmaf(v, v, s2); }
        const float mu = s * 0.03125f;
        const float inv = rsqrtf(s2 * 0.03125f - mu * mu + 1e-5f);
        #pragma unroll
        for (int m = 0; m < 32; ++m)
            xr[rr][m] = (xr[rr][m] - mu) * inv * g1[m] + beta1[m];
        unsigned* sp = reinterpret_cast<unsigned*>(reinterpret_cast<char*>(st) + r * 72);
        #pragma unroll
        for (int d2 = 0; d2 < 16; ++d2)
            sp[d2] = (unsigned)f2bf(xr[rr][2*d2]) | ((unsigned)f2bf(xr[rr][2*d2+1]) << 16);
    }
    __syncthreads();

    // coalesced xln store (row-major [512][32])
    {
        uint4* dst = reinterpret_cast<uint4*>(xln + blk * 16384);
        #pragma unroll
        for (int i = 0; i < 8; ++i) {
            const int o = (i * 256 + tid) * 8;
            const int row = o >> 5, c = o & 31;
            const uint2* sp = reinterpret_cast<const uint2*>(reinterpret_cast<char*>(st) + row * 72 + c * 2);
            uint2 a = sp[0], b2 = sp[1];
            dst[o >> 3] = make_uint4(a.x, a.y, b2.x, b2.y);
        }
    }

    // q/k/v = xln @ W[h]   (W broadcast from LDS, accumulate in regs)
    for (int mat = 0; mat < 3; ++mat) {
        float rq[2][32];
        #pragma unroll
        for (int i = 0; i < 32; ++i) { rq[0][i] = 0.f; rq[1][i] = 0.f; }
        const float4* wp = reinterpret_cast<const float4*>(Wsh + mat * 1024);
        #pragma unroll
        for (int h = 0; h < 2; ++h) {
            for (int m = 0; m < 32; ++m) {
                const float x0 = xr[0][m], x1 = xr[1][m];
                #pragma unroll
                for (int g = 0; g < 4; ++g) {
                    const float4 wv4 = wp[h * 128 + m * 4 + g];
                    rq[0][h*16+g*4+0] = fmaf(x0, wv4.x, rq[0][h*16+g*4+0]);
                    rq[0][h*16+g*4+1] = fmaf(x0, wv4.y, rq[0][h*16+g*4+1]);
                    rq[0][h*16+g*4+2] = fmaf(x0, wv4.z, rq[0][h*16+g*4+2]);
                    rq[0][h*16+g*4+3] = fmaf(x0, wv4.w, rq[0][h*16+g*4+3]);
                    rq[1][h*16+g*4+0] = fmaf(x1, wv4.x, rq[1][h*16+g*4+0]);
                    rq[1][h*16+g*4+1] = fmaf(x1, wv4.y, rq[1][h*16+g*4+1]);
                    rq[1][h*16+g*4+2] = fmaf(x1, wv4.z, rq[1][h*16+g*4+2]);
                    rq[1][h*16+g*4+3] = fmaf(x1, wv4.w, rq[1][h*16+g*4+3]);
                }
            }
        }
        __syncthreads();  // prior st readers done
        #pragma unroll
        for (int rr = 0; rr < 2; ++rr) {
            const int r = tid + rr * 256;
            unsigned* sp = reinterpret_cast<unsigned*>(reinterpret_cast<char*>(st) + r * 72);
            #pragma unroll
            for (int d2 = 0; d2 < 16; ++d2)
                sp[d2] = (unsigned)f2bf(rq[rr][2*d2]) | ((unsigned)f2bf(rq[rr][2*d2+1]) << 16);
        }
        __syncthreads();
        unsigned short* wsout = (mat == 0) ? qw : (mat == 1 ? kw : vw);
        uint4* dst = reinterpret_cast<uint4*>(wsout + blk * 16384);
        #pragma unroll
        for (int i = 0; i < 8; ++i) {
            const int o = (i * 256 + tid) * 8;
            const int bb = o >> 12, hh = (o >> 11) & 1, tt = (o >> 4) & 127;
            const int row = (bb << 7) | tt, c = (hh << 4) | (o & 15);
            const uint2* sp = reinterpret_cast<const uint2*>(reinterpret_cast<char*>(st) + row * 72 + c * 2);
            uint2 a = sp[0], b2 = sp[1];
            dst[o >> 3] = make_uint4(a.x, a.y, b2.x, b2.y);
        }
    }
}

// ---------------------------------------------------------------- kernel B
// grid 2048 (one batch elem), block 256: thread = (h, t) for attention,
// then (half, r) for Wo/LN2.
__global__ __launch_bounds__(256, 3) void kB(
    const unsigned short* __restrict__ xln, const unsigned short* __restrict__ qw,
    const unsigned short* __restrict__ kw, const unsigned short* __restrict__ vw,
    const float* __restrict__ Wo, const float* __restrict__ bo,
    const float* __restrict__ g2, const float* __restrict__ beta2,
    unsigned short* __restrict__ x3)
{
    __shared__ float kvf[8192];     // K [2][128][16] @0, V @4096 (f32)
    __shared__ float ax[128 * 33];  // attn rows, then x2
    const int tid = threadIdx.x;
    const size_t b = blockIdx.x;

    {
        const uint4* kg = reinterpret_cast<const uint4*>(kw + b * 4096);
        const uint4* vg = reinterpret_cast<const uint4*>(vw + b * 4096);
        #pragma unroll
        for (int i = 0; i < 2; ++i) {
            const int o = i * 256 + tid;
            const uint4 kp = kg[o], vp = vg[o];
            float* kd = kvf + o * 8;
            float* vd = kvf + 4096 + o * 8;
            kd[0]=bflo(kp.x); kd[1]=bfhi(kp.x); kd[2]=bflo(kp.y); kd[3]=bfhi(kp.y);
            kd[4]=bflo(kp.z); kd[5]=bfhi(kp.z); kd[6]=bflo(kp.w); kd[7]=bfhi(kp.w);
            vd[0]=bflo(vp.x); vd[1]=bfhi(vp.x); vd[2]=bflo(vp.y); vd[3]=bfhi(vp.y);
            vd[4]=bflo(vp.z); vd[5]=bfhi(vp.z); vd[6]=bflo(vp.w); vd[7]=bfhi(vp.w);
        }
    }
    __syncthreads();

    const int h = tid >> 7, t = tid & 127;
    float q[16];
    {
        const uint4* qg = reinterpret_cast<const uint4*>(qw + b * 4096 + (h << 11) + (t << 4));
        const uint4 q0 = qg[0], q1 = qg[1];
        q[0]=bflo(q0.x); q[1]=bfhi(q0.x); q[2]=bflo(q0.y); q[3]=bfhi(q0.y);
        q[4]=bflo(q0.z); q[5]=bfhi(q0.z); q[6]=bflo(q0.w); q[7]=bfhi(q0.w);
        q[8]=bflo(q1.x); q[9]=bfhi(q1.x); q[10]=bflo(q1.y); q[11]=bfhi(q1.y);
        q[12]=bflo(q1.z); q[13]=bfhi(q1.z); q[14]=bflo(q1.w); q[15]=bfhi(q1.w);
    }

    float acc[16];
    #pragma unroll
    for (int i = 0; i < 16; ++i) acc[i] = 0.f;
    float lsum = 0.f;
    {
        const float4* kk = reinterpret_cast<const float4*>(kvf + (h << 11));
        const float4* vv = reinterpret_cast<const float4*>(kvf + 4096 + (h << 11));
        for (int s = 0; s <= t; ++s) {
            const float4 k0 = kk[s*4+0], k1 = kk[s*4+1], k2 = kk[s*4+2], k3 = kk[s*4+3];
            const float p0 = fmaf(q[0],  k0.x, fmaf(q[1],  k0.y, fmaf(q[2],  k0.z, q[3]  * k0.w)));
            const float p1 = fmaf(q[4],  k1.x, fmaf(q[5],  k1.y, fmaf(q[6],  k1.z, q[7]  * k1.w)));
            const float p2 = fmaf(q[8],  k2.x, fmaf(q[9],  k2.y, fmaf(q[10], k2.z, q[11] * k2.w)));
            const float p3 = fmaf(q[12], k3.x, fmaf(q[13], k3.y, fmaf(q[14], k3.z, q[15] * k3.w)));
            const float p = __expf((p0 + p1) + (p2 + p3));
            lsum += p;
            const float4 v0 = vv[s*4+0], v1 = vv[s*4+1], v2 = vv[s*4+2], v3 = vv[s*4+3];
            acc[0] =fmaf(p,v0.x,acc[0]);  acc[1] =fmaf(p,v0.y,acc[1]);
            acc[2] =fmaf(p,v0.z,acc[2]);  acc[3] =fmaf(p,v0.w,acc[3]);
            acc[4] =fmaf(p,v1.x,acc[4]);  acc[5] =fmaf(p,v1.y,acc[5]);
            acc[6] =fmaf(p,v1.z,acc[6]);  acc[7] =fmaf(p,v1.w,acc[7]);
            acc[8] =fmaf(p,v2.x,acc[8]);  acc[9] =fmaf(p,v2.y,acc[9]);
            acc[10]=fmaf(p,v2.z,acc[10]); acc[11]=fmaf(p,v2.w,acc[11]);
            acc[12]=fmaf(p,v3.x,acc[12]); acc[13]=fmaf(p,v3.y,acc[13]);
            acc[14]=fmaf(p,v3.z,acc[14]); acc[15]=fmaf(p,v3.w,acc[15]);
        }
    }
    const float linv = 1.f / lsum;
    #pragma unroll
    for (int i = 0; i < 16; ++i) ax[t * 33 + (h << 4) + i] = acc[i] * linv;
    __syncthreads();

    // x2 = xln + attn @ Wo + bo   (thread = 16 cols of one row)
    const int r = tid & 127, c0 = (tid >> 7) << 4;
    float a2[16];
    {
        const uint4* xlp = reinterpret_cast<const uint4*>(xln + (b * 128 + r) * 32 + c0);
        const uint4 xa = xlp[0], xb = xlp[1];
        a2[0]=bflo(xa.x); a2[1]=bfhi(xa.x); a2[2]=bflo(xa.y); a2[3]=bfhi(xa.y);
        a2[4]=bflo(xa.z); a2[5]=bfhi(xa.z); a2[6]=bflo(xa.w); a2[7]=bfhi(xa.w);
        a2[8]=bflo(xb.x); a2[9]=bfhi(xb.x); a2[10]=bflo(xb.y); a2[11]=bfhi(xb.y);
        a2[12]=bflo(xb.z); a2[13]=bfhi(xb.z); a2[14]=bflo(xb.w); a2[15]=bfhi(xb.w);
        #pragma unroll
        for (int i = 0; i < 16; ++i) a2[i] += bo[c0 + i];
    }
    for (int m = 0; m < 32; ++m) {
        const float av = ax[r * 33 + m];
        const float4* w4 = reinterpret_cast<const float4*>(Wo + m * 32 + c0);
        #pragma unroll
        for (int g = 0; g < 4; ++g) {
            const float4 w = w4[g];
            a2[g*4+0] = fmaf(av, w.x, a2[g*4+0]);
            a2[g*4+1] = fmaf(av, w.y, a2[g*4+1]);
            a2[g*4+2] = fmaf(av, w.z, a2[g*4+2]);
            a2[g*4+3] = fmaf(av, w.w, a2[g*4+3]);
        }
    }
    __syncthreads();
    #pragma unroll
    for (int i = 0; i < 16; ++i) ax[r * 33 + c0 + i] = a2[i];
    __syncthreads();

    // LN2 -> x3 (bf16)
    float s = 0.f, s2 = 0.f;
    #pragma unroll
    for (int c = 0; c < 32; ++c) { const float v = ax[r * 33 + c]; s += v; s2 = fmaf(v, v, s2); }
    const float mu = s * 0.03125f;
    const float inv = rsqrtf(s2 * 0.03125f - mu * mu + 1e-5f);
    unsigned o8[8];
    #pragma unroll
    for (int d2 = 0; d2 < 8; ++d2) {
        const float v0 = (a2[2*d2]   - mu) * inv * g2[c0 + 2*d2]   + beta2[c0 + 2*d2];
        const float v1 = (a2[2*d2+1] - mu) * inv * g2[c0 + 2*d2+1] + beta2[c0 + 2*d2+1];
        o8[d2] = (unsigned)f2bf(v0) | ((unsigned)f2bf(v1) << 16);
    }
    uint4* dst = reinterpret_cast<uint4*>(x3 + (b * 128 + r) * 32 + c0);
    dst[0] = make_uint4(o8[0], o8[1], o8[2], o8[3]);
    dst[1] = make_uint4(o8[4], o8[5], o8[6], o8[7]);
}

// ---------------------------------------------------------------- kernel C
// grid 1024, block 256 (4 waves). 256 rows/block, 4 m-tiles/wave.
// out = x3 + relu(x3@W1 + b1)@W2 + b2, MFMA 16x16x32 bf16.
__global__ __launch_bounds__(256, 3) void kC(
    const unsigned short* __restrict__ x3, const float* __restrict__ W1,
    const float* __restrict__ b1, const float* __restrict__ W2,
    const float* __restrict__ b2, float* __restrict__ out)
{
    __shared__ unsigned short x3s[256 * 36];      // rows padded to 72 B
    __shared__ unsigned short hbuf[4 * 16 * 132]; // per-wave h strip [16][132]
    const int tid = threadIdx.x;
    const size_t blk = blockIdx.x;
    const int lane = tid & 63, w = tid >> 6;
    const int ln15 = lane & 15, g4 = lane >> 4;

    {
        const uint4* src = reinterpret_cast<const uint4*>(x3 + blk * 8192);
        #pragma unroll
        for (int i = 0; i < 4; ++i) {
            const int idx = i * 256 + tid;
            const uint4 vgl = src[idx];
            const int o = idx * 8, row = o >> 5, c = o & 31;
            uint2* d = reinterpret_cast<uint2*>(reinterpret_cast<char*>(x3s) + row * 72 + c * 2);
            d[0] = make_uint2(vgl.x, vgl.y);
            d[1] = make_uint2(vgl.z, vgl.w);
        }
    }

    // weight fragments in registers (L1/L2-cached scalar loads, once)
    // frag elem j holds W[k][n], k = (j&3) + 4*g4 + 16*(j>>2), n = nt*16 + ln15
    short8x w1f[8]; float b1v[8];
    #pragma unroll
    for (int nt = 0; nt < 8; ++nt) {
        union { short e[8]; short8x v; } u;
        #pragma unroll
        for (int j = 0; j < 8; ++j) {
            const int k = (j & 3) + 4 * g4 + 16 * (j >> 2);
            u.e[j] = (short)f2bf(W1[k * 128 + nt * 16 + ln15]);
        }
        w1f[nt] = u.v;
        b1v[nt] = b1[nt * 16 + ln15];
    }
    short8x w2f[4][2]; float b2v[2];
    #pragma unroll
    for (int nt2 = 0; nt2 < 2; ++nt2) {
        b2v[nt2] = b2[nt2 * 16 + ln15];
        #pragma unroll
        for (int kc = 0; kc < 4; ++kc) {
            union { short e[8]; short8x v; } u;
            #pragma unroll
            for (int j = 0; j < 8; ++j) {
                const int k = kc * 32 + (j & 3) + 4 * g4 + 16 * (j >> 2);
                u.e[j] = (short)f2bf(W2[k * 32 + nt2 * 16 + ln15]);
            }
            w2f[kc][nt2] = u.v;
        }
    }
    __syncthreads();

    unsigned short* hb = hbuf + w * 2112;
    for (int mi = 0; mi < 4; ++mi) {
        const int mt = w * 4 + mi, rowb = mt * 16;
        short8x xa;
        {
            const char* base = reinterpret_cast<const char*>(x3s) + (rowb + ln15) * 72 + g4 * 8;
            union { uint2 u2[2]; short8x v; } u;
            u.u2[0] = *reinterpret_cast<const uint2*>(base);
            u.u2[1] = *reinterpret_cast<const uint2*>(base + 32);
            xa = u.v;
        }
        #pragma unroll
        for (int nt = 0; nt < 8; ++nt) {
            f32x4 acc = {0.f, 0.f, 0.f, 0.f};
            acc = __builtin_amdgcn_mfma_f32_16x16x32_bf16(xa, w1f[nt], acc, 0, 0, 0);
            #pragma unroll
            for (int rq = 0; rq < 4; ++rq) {
                const float hv = fmaxf(acc[rq] + b1v[nt], 0.f);
                hb[(4 * g4 + rq) * 132 + nt * 16 + ln15] = f2bf(hv);
            }
        }
        asm volatile("s_waitcnt lgkmcnt(0)" ::: "memory");
        #pragma unroll
        for (int nt2 = 0; nt2 < 2; ++nt2) {
            f32x4 acc = {0.f, 0.f, 0.f, 0.f};
            #pragma unroll
            for (int kc = 0; kc < 4; ++kc) {
                const char* base = reinterpret_cast<const char*>(hb) + ln15 * 264 + kc * 64 + g4 * 8;
                union { uint2 u2[2]; short8x v; } u;
                u.u2[0] = *reinterpret_cast<const uint2*>(base);
                u.u2[1] = *reinterpret_cast<const uint2*>(base + 32);
                acc = __builtin_amdgcn_mfma_f32_16x16x32_bf16(u.v, w2f[kc][nt2], acc, 0, 0, 0);
            }
            #pragma unroll
            for (int rq = 0; rq < 4; ++rq) {
                const int row = rowb + 4 * g4 + rq, col = nt2 * 16 + ln15;
                const float res = bf2f(x3s[row * 36 + col]);
                out[(blk * 256 + row) * 32 + col] = acc[rq] + b2v[nt2] + res;
            }
        }
    }
}

// ---------------------------------------------------------------- launch
extern "C" void kernel_launch(void* const* d_in, const int* in_sizes, int n_in,
                              void* d_out, int out_size, void* d_ws, size_t ws_size,
                              hipStream_t stream) {
    const float* x   = (const float*)d_in[0];
    const float* Wq  = (const float*)d_in[1];
    const float* Wk  = (const float*)d_in[2];
    const float* Wv  = (const float*)d_in[3];
    const float* Wo  = (const float*)d_in[4];
    const float* bo  = (const float*)d_in[5];
    const float* W1  = (const float*)d_in[6];
    const float* b1  = (const float*)d_in[7];
    const float* W2  = (const float*)d_in[8];
    const float* b2  = (const float*)d_in[9];
    const float* g1  = (const float*)d_in[10];
    const float* be1 = (const float*)d_in[11];
    const float* g2  = (const float*)d_in[12];
    const float* be2 = (const float*)d_in[13];
    float* outp = (float*)d_out;

    unsigned short* wsu = (unsigned short*)d_ws;
    const size_t CH = 8388608;  // elements per chunk (16.78 MB)
    unsigned short* xln = wsu;
    unsigned short* qws = wsu + CH;
    unsigned short* kws = wsu + 2 * CH;
    unsigned short* vws = wsu + 3 * CH;
    unsigned short* x3  = wsu + 4 * CH;

    hipLaunchKernelGGL(kA, dim3(512), dim3(256), 0, stream,
                       x, Wq, Wk, Wv, g1, be1, xln, qws, kws, vws);
    hipLaunchKernelGGL(kB, dim3(2048), dim3(256), 0, stream,
                       xln, qws, kws, vws, Wo, bo, g2, be2, x3);
    hipLaunchKernelGGL(kC, dim3(1024), dim3(256), 0, stream,
                       x3, W1, b1, W2, b2, outp);
}